// Round 15
// baseline (111.530 us; speedup 1.0000x reference)
//
#include <hip/hip_runtime.h>
#include <hip/hip_fp16.h>

// Fused WeightedMAE + Patch-SSIM loss for (8,8,512,512) fp32 inputs.
// R15 = R12's 3-strip geometry (19.9 KB LDS -> 8 blocks/CU ceiling) +
// amdgpu_waves_per_eu(4,8): min=4 sets the VGPR budget to 128 so the
// compiler keeps its natural ~44-52 allocation (R12's collapse to 28 regs
// was the whole regression: 108 us @ 50% busy), max=8 lets the scheduler
// still pack up to 8 blocks/CU for fetch/compute overlap (R9 lesson).
// 12288 blocks = 4096 (patch,channel) x 3 strips; 256 threads.
// Strip s: output rows 18s..18s+17, staged input rows 18s..18s+27.
// Phase A: float4 loads of 28 rows, stage (x,y) packed half2, fused MAE.
// Phase V: vertical 11-tap conv {x,y,xx,yy,xy} packed fp16 (hfma2);
//          wave g owns {5,5,4,4} rows, lane = col; uniform guards only.
// Phase H: horizontal conv, 18 rows x 14 groups of 4 cols = 252 units,
//          1/thread; b64 window reads; SSIM with v_rcp_f32.
// LDS = 7168(xyt) + 5040(V01) + 5040(V23) + 2520(V4) + 48 = 19816 B.

#define C1c 1.0e-4f
#define C2c 9.0e-4f
#define NSLOT 64

struct alignas(16) xy4  { __half2 v[4]; };
struct alignas(8)  h2x2 { __half2 a, b; };

__global__ __launch_bounds__(256)
__attribute__((amdgpu_waves_per_eu(4, 8)))
void fused_loss_kernel(const float* __restrict__ in,
                       const float* __restrict__ outp,
                       const float* __restrict__ tgt,
                       float* __restrict__ ws) {
    __shared__ alignas(16) __half2 xyt[28][64];   // (x,y) per pixel, 7168 B
    __shared__ alignas(16) __half2 V01[18][70];   // (Gv*x, Gv*y)
    __shared__ alignas(16) __half2 V23[18][70];   // (Gv*xx, Gv*yy)
    __shared__ alignas(16) __half  V4 [18][70];   // Gv*xy
    __shared__ float red[4][3];

    // exp(-(j-5)^2/4.5)/sum, float32 pipeline (HW-validated)
    const float WGT[11] = {0.00102838f, 0.00759874f, 0.03600076f, 0.10936068f,
                           0.21300564f, 0.26601172f, 0.21300564f, 0.10936068f,
                           0.03600076f, 0.00759874f, 0.00102838f};
    __half  WH[11];
    __half2 WH2[11];
#pragma unroll
    for (int j = 0; j < 11; ++j) {                // constant-folded
        WH[j]  = __float2half_rn(WGT[j]);
        WH2[j] = __half2half2(WH[j]);
    }

    const int tid = threadIdx.x;

    // XCD-contiguous bijective swizzle (12288 = 8 * 1536)
    const int orig    = blockIdx.x;
    const int logical = (orig & 7) * 1536 + (orig >> 3);
    const int pc      = logical / 3;              // 0..4095
    const int s       = logical - pc * 3;         // strip 0..2
    const int ch      = pc & 7;
    const int p       = pc >> 3;
    const int b       = p >> 6;
    const int ph      = (p >> 3) & 7;
    const int pw      = p & 7;
    const int r0      = s * 18;                   // first staged input row

    // ---------------- Phase A: float4 load 28 rows, stage, fused MAE ------
    float mae_num = 0.0f, mae_den = 0.0f;
    const size_t img_base =
        ((size_t)(b * 8 + ch) * 512 + (size_t)(ph * 64 + r0)) * 512 +
        (size_t)(pw * 64);
    const bool own_all = (s == 2);

#pragma unroll
    for (int it = 0; it < 2; ++it) {
        const int slot = tid + it * 256;          // 0..447 (28 rows x 16)
        if (slot < 448) {
            const int r  = slot >> 4;             // 0..27
            const int c4 = (slot & 15) << 2;      // 0..60
            const size_t off = img_base + (size_t)r * 512 + (size_t)c4;
            const float4 iv = *(const float4*)(in   + off);
            const float4 ov = *(const float4*)(outp + off);
            const float4 tv = *(const float4*)(tgt  + off);
            xy4 q;
            q.v[0] = __floats2half2_rn(iv.x + ov.x, tv.x);
            q.v[1] = __floats2half2_rn(iv.y + ov.y, tv.y);
            q.v[2] = __floats2half2_rn(iv.z + ov.z, tv.z);
            q.v[3] = __floats2half2_rn(iv.w + ov.w, tv.w);
            *(xy4*)&xyt[r][c4] = q;
            if (r < 18 || own_all) {              // each image row MAE'd once
                float hp, w;
                hp = tv.x - iv.x; w = (fabsf(hp) > 0.0f) ? 1.0f : 0.0f;
                mae_den += w; mae_num = fmaf(w, fabsf(ov.x - hp), mae_num);
                hp = tv.y - iv.y; w = (fabsf(hp) > 0.0f) ? 1.0f : 0.0f;
                mae_den += w; mae_num = fmaf(w, fabsf(ov.y - hp), mae_num);
                hp = tv.z - iv.z; w = (fabsf(hp) > 0.0f) ? 1.0f : 0.0f;
                mae_den += w; mae_num = fmaf(w, fabsf(ov.z - hp), mae_num);
                hp = tv.w - iv.w; w = (fabsf(hp) > 0.0f) ? 1.0f : 0.0f;
                mae_den += w; mae_num = fmaf(w, fabsf(ov.w - hp), mae_num);
            }
        }
    }
    __syncthreads();

    // ---------------- Phase V: vertical conv, wave-per-row-block ----------
    // Wave g owns out rows: g<2 -> 5 rows at 5g; else 4 rows at 10+4(g-2).
    {
        const int c     = tid & 63;
        const int g     = tid >> 6;               // wave-uniform
        const bool big  = (g < 2);
        const int rb    = big ? g * 5 : 10 + (g - 2) * 4;

        __half2 a01[5], a23[5];
        __half  a4[5];
#pragma unroll
        for (int i = 0; i < 5; ++i) {
            a01[i] = __half2half2(__float2half_rn(0.0f));
            a23[i] = a01[i];
            a4[i]  = __float2half_rn(0.0f);
        }
#pragma unroll
        for (int ir = 0; ir < 15; ++ir) {
            if (ir < 14 || big) {                 // wave-uniform (ir==14)
                const __half2 q   = xyt[rb + ir][c];
                const __half2 qq  = __hmul2(q, q);
                const __half  xyh = __hmul(__low2half(q), __high2half(q));
#pragma unroll
                for (int i = 0; i < 5; ++i) {
                    const int j = ir - i;
                    if (j >= 0 && j <= 10) {      // folds at compile time
                        if (i < 4 || big) {       // wave-uniform (i==4)
                            a01[i] = __hfma2(WH2[j], q,  a01[i]);
                            a23[i] = __hfma2(WH2[j], qq, a23[i]);
                            a4[i]  = __hfma(WH[j], xyh, a4[i]);
                        }
                    }
                }
            }
        }
#pragma unroll
        for (int i = 0; i < 5; ++i) {
            if (i < 4 || big) {
                V01[rb + i][c] = a01[i];
                V23[rb + i][c] = a23[i];
                V4 [rb + i][c] = a4[i];
            }
        }
    }
    __syncthreads();

    // ---------------- Phase H: horizontal conv + SSIM, 1 unit/thread ------
    // 18 rows x 14 groups (4 out cols) = 252 units.
    float ssim_acc = 0.0f;
    if (tid < 252) {
        const int row = tid / 14;
        const int grp = tid - row * 14;
        const int c0  = grp << 2;                 // 0,4,..,52

        __half2 w01[16], w23[16];
        __half  w4[16];
        {
            const __half2* r01 = &V01[row][c0];
            const __half2* r23 = &V23[row][c0];
            const __half*  r4  = &V4 [row][c0];
#pragma unroll
            for (int t = 0; t < 8; ++t) {         // 8B h2x2 / 4B half2 reads
                const h2x2 qa = *(const h2x2*)(r01 + 2 * t);
                w01[2*t] = qa.a; w01[2*t+1] = qa.b;
                const h2x2 qb = *(const h2x2*)(r23 + 2 * t);
                w23[2*t] = qb.a; w23[2*t+1] = qb.b;
                const __half2 qc = *(const __half2*)(r4 + 2 * t);
                w4[2*t] = __low2half(qc); w4[2*t+1] = __high2half(qc);
            }
        }
#pragma unroll
        for (int k = 0; k < 4; ++k) {
            if (grp < 13 || k < 2) {              // 4*grp+k < 54
                __half2 s01 = __half2half2(__float2half_rn(0.0f));
                __half2 s23 = s01;
                __half  s4  = __float2half_rn(0.0f);
#pragma unroll
                for (int j = 0; j < 11; ++j) {
                    s01 = __hfma2(WH2[j], w01[k + j], s01);
                    s23 = __hfma2(WH2[j], w23[k + j], s23);
                    s4  = __hfma(WH[j], w4[k + j], s4);
                }
                const float mu1 = __low2float(s01);
                const float mu2 = __high2float(s01);
                const float sxx = __low2float(s23);
                const float syy = __high2float(s23);
                const float sxy = __half2float(s4);
                const float mu1sq = mu1 * mu1;
                const float mu2sq = mu2 * mu2;
                const float mu12  = mu1 * mu2;
                const float num = (2.0f * mu12 + C1c) * (2.0f * (sxy - mu12) + C2c);
                const float den = (mu1sq + mu2sq + C1c) *
                                  ((sxx - mu1sq) + (syy - mu2sq) + C2c);
                ssim_acc = fmaf(num, __builtin_amdgcn_rcpf(den), ssim_acc);
            }
        }
    }

    // ---------------- Reduction -> slotted atomics ------------------------
    float v0 = mae_num, v1 = mae_den, v2 = ssim_acc;
#pragma unroll
    for (int off = 32; off >= 1; off >>= 1) {
        v0 += __shfl_down(v0, off);
        v1 += __shfl_down(v1, off);
        v2 += __shfl_down(v2, off);
    }
    const int wave = tid >> 6;
    const int lane = tid & 63;
    if (lane == 0) { red[wave][0] = v0; red[wave][1] = v1; red[wave][2] = v2; }
    __syncthreads();
    if (tid == 0) {
        float r0s = 0.f, r1s = 0.f, r2s = 0.f;
#pragma unroll
        for (int w = 0; w < 4; ++w) {
            r0s += red[w][0]; r1s += red[w][1]; r2s += red[w][2];
        }
        const int slot = logical & (NSLOT - 1);
        atomicAdd(&ws[slot * 3 + 0], r0s);
        atomicAdd(&ws[slot * 3 + 1], r1s);
        atomicAdd(&ws[slot * 3 + 2], r2s);
    }
}

__global__ void finalize_kernel(const float* __restrict__ ws, float* __restrict__ out) {
    if (threadIdx.x == 0 && blockIdx.x == 0) {
        float r0 = 0.f, r1 = 0.f, r2 = 0.f;
        for (int i = 0; i < NSLOT; ++i) {
            r0 += ws[i * 3 + 0];
            r1 += ws[i * 3 + 1];
            r2 += ws[i * 3 + 2];
        }
        const float mae = r0 / (r1 + 1e-8f);
        const float ssim_mean = r2 * (1.0f / 11943936.0f);  // 4096 * 54 * 54
        out[0] = 0.5f * mae + 0.5f * (1.0f - ssim_mean);
    }
}

extern "C" void kernel_launch(void* const* d_in, const int* in_sizes, int n_in,
                              void* d_out, int out_size, void* d_ws, size_t ws_size,
                              hipStream_t stream) {
    const float* in   = (const float*)d_in[0];
    const float* outp = (const float*)d_in[1];
    const float* tgt  = (const float*)d_in[2];
    float* ws = (float*)d_ws;

    hipMemsetAsync(d_ws, 0, NSLOT * 3 * sizeof(float), stream);
    fused_loss_kernel<<<12288, 256, 0, stream>>>(in, outp, tgt, ws);
    finalize_kernel<<<1, 64, 0, stream>>>(ws, (float*)d_out);
}

// Round 16
// 75.254 us; speedup vs baseline: 1.4821x; 1.4821x over previous
//
#include <hip/hip_runtime.h>
#include <hip/hip_fp16.h>

// Fused WeightedMAE + Patch-SSIM loss for (8,8,512,512) fp32 inputs.
// R16 = R14 (best, 75us: single barrier, wave-local V->H, 5-block LDS)
// + amdgpu_waves_per_eu(5,5). R15 lesson: regalloc targets the window MAX
// (4,8 -> 28 regs, same as none); only min==max pins it. (5,5) = budget
// 102 VGPRs (natural 44-52 fits) AND scheduler packs 5 blocks/CU = 20
// waves (R14 measured only ~14).
// 8192 blocks = 4096 (patch,channel) x 2 halves; 256 threads.
// Phase A: float4 loads of 37 rows, stage (x,y) packed half2, fused MAE.
// Phase V: vertical 11-tap conv {x,y,xx,yy,xy} packed fp16 (hfma2);
//          wave g owns 7 rows (g=3: 6), lane = col.
// Phase H (same wave, NO barrier: intra-wave LDS RAW lgkmcnt-ordered):
//          horizontal conv, 7 rows x 9 groups = 63 units on 64 lanes,
//          b64 window reads; SSIM with v_rcp_f32.
// LDS = 9.25(xyt) + 6.96(V01) + 6.96(V23) + 3.59(V4) KB ~= 26.8 KB.

#define C1c 1.0e-4f
#define C2c 9.0e-4f
#define NSLOT 64

struct alignas(16) xy4  { __half2 v[4]; };
struct alignas(8)  h2x2 { __half2 a, b; };

__global__ __launch_bounds__(256)
__attribute__((amdgpu_waves_per_eu(5, 5)))
void fused_loss_kernel(const float* __restrict__ in,
                       const float* __restrict__ outp,
                       const float* __restrict__ tgt,
                       float* __restrict__ ws) {
    __shared__ alignas(16) __half2 xyt[37][64];   // (x,y) per pixel
    __shared__ alignas(16) __half2 V01[27][66];   // (Gv*x, Gv*y), padded
    __shared__ alignas(16) __half2 V23[27][66];   // (Gv*xx, Gv*yy), padded
    __shared__ alignas(16) __half  V4 [27][68];   // Gv*xy
    __shared__ float red[4][3];

    // exp(-(j-5)^2/4.5)/sum, float32 pipeline (HW-validated)
    const float WGT[11] = {0.00102838f, 0.00759874f, 0.03600076f, 0.10936068f,
                           0.21300564f, 0.26601172f, 0.21300564f, 0.10936068f,
                           0.03600076f, 0.00759874f, 0.00102838f};
    __half  WH[11];
    __half2 WH2[11];
#pragma unroll
    for (int j = 0; j < 11; ++j) {       // constant-folded
        WH[j]  = __float2half_rn(WGT[j]);
        WH2[j] = __half2half2(WH[j]);
    }

    const int tid = threadIdx.x;

    // XCD-contiguous swizzle (8192 = 8 * 1024)
    const int orig    = blockIdx.x;
    const int logical = (orig & 7) * 1024 + (orig >> 3);
    const int half    = logical & 1;
    const int pc      = logical >> 1;
    const int ch      = pc & 7;
    const int p       = pc >> 3;
    const int b       = p >> 6;
    const int ph      = (p >> 3) & 7;
    const int pw      = p & 7;
    const int r0      = half ? 27 : 0;

    // ---------------- Phase A: float4 load 37 rows, stage, fused MAE ------
    float mae_num = 0.0f, mae_den = 0.0f;
    const size_t img_base =
        ((size_t)(b * 8 + ch) * 512 + (size_t)(ph * 64 + r0)) * 512 +
        (size_t)(pw * 64);

#pragma unroll
    for (int it = 0; it < 3; ++it) {
        const int slot = tid + it * 256;        // 0..591
        if (slot < 592) {
            const int r  = slot >> 4;           // 0..36
            const int c4 = (slot & 15) << 2;    // 0..60
            const size_t off = img_base + (size_t)r * 512 + (size_t)c4;
            const float4 iv = *(const float4*)(in   + off);
            const float4 ov = *(const float4*)(outp + off);
            const float4 tv = *(const float4*)(tgt  + off);
            xy4 q;
            q.v[0] = __floats2half2_rn(iv.x + ov.x, tv.x);
            q.v[1] = __floats2half2_rn(iv.y + ov.y, tv.y);
            q.v[2] = __floats2half2_rn(iv.z + ov.z, tv.z);
            q.v[3] = __floats2half2_rn(iv.w + ov.w, tv.w);
            *(xy4*)&xyt[r][c4] = q;
            const bool own = half ? (r >= 5) : (r < 32);
            if (own) {
                float hp, w;
                hp = tv.x - iv.x; w = (fabsf(hp) > 0.0f) ? 1.0f : 0.0f;
                mae_den += w; mae_num = fmaf(w, fabsf(ov.x - hp), mae_num);
                hp = tv.y - iv.y; w = (fabsf(hp) > 0.0f) ? 1.0f : 0.0f;
                mae_den += w; mae_num = fmaf(w, fabsf(ov.y - hp), mae_num);
                hp = tv.z - iv.z; w = (fabsf(hp) > 0.0f) ? 1.0f : 0.0f;
                mae_den += w; mae_num = fmaf(w, fabsf(ov.z - hp), mae_num);
                hp = tv.w - iv.w; w = (fabsf(hp) > 0.0f) ? 1.0f : 0.0f;
                mae_den += w; mae_num = fmaf(w, fabsf(ov.w - hp), mae_num);
            }
        }
    }
    __syncthreads();                            // the ONLY barrier

    const int lane = tid & 63;
    const int g    = tid >> 6;                  // wave index, uniform
    const int rb   = g * 7;                     // first owned out row
    const int nrows = (g == 3) ? 6 : 7;

    // ---------------- Phase V: vertical conv, wave-local rows -------------
    {
        const int c     = lane;
        const int nread = (g == 3) ? 16 : 17;

        __half2 a01[7], a23[7];
        __half  a4[7];
#pragma unroll
        for (int i = 0; i < 7; ++i) {
            a01[i] = __half2half2(__float2half_rn(0.0f));
            a23[i] = a01[i];
            a4[i]  = __float2half_rn(0.0f);
        }
#pragma unroll
        for (int ir = 0; ir < 17; ++ir) {
            if (ir < nread) {                   // wave-uniform
                const __half2 q  = xyt[rb + ir][c];
                const __half2 qq = __hmul2(q, q);
                const __half  xyh = __hmul(__low2half(q), __high2half(q));
#pragma unroll
                for (int i = 0; i < 7; ++i) {
                    const int j = ir - i;
                    if (j >= 0 && j <= 10) {    // folds at compile time
                        if (i < 6 || g < 3) {   // wave-uniform (i==6 only)
                            a01[i] = __hfma2(WH2[j], q,  a01[i]);
                            a23[i] = __hfma2(WH2[j], qq, a23[i]);
                            a4[i]  = __hfma(WH[j], xyh, a4[i]);
                        }
                    }
                }
            }
        }
#pragma unroll
        for (int i = 0; i < 7; ++i) {
            if (i < 6 || g < 3) {
                V01[rb + i][c] = a01[i];
                V23[rb + i][c] = a23[i];
                V4 [rb + i][c] = a4[i];
            }
        }
    }
    // NO BARRIER: wave g reads back only rows rb..rb+nrows-1, which this
    // same wave wrote; LDS ops are in-order within a wave (lgkmcnt).

    // ---------------- Phase H: wave-local horizontal conv + SSIM ----------
    // nrows x 9 groups (6 out cols) = 63 (54) units on 64 lanes.
    float ssim_acc = 0.0f;
    if (lane < nrows * 9) {
        const int row_l = lane / 9;
        const int grp   = lane - row_l * 9;
        const int row   = rb + row_l;
        const int c0    = grp * 6;              // 0,6,..,48

        __half2 w01[16], w23[16];
        __half  w4[16];
        {
            const __half2* r01 = &V01[row][c0];
            const __half2* r23 = &V23[row][c0];
            const __half*  r4  = &V4 [row][c0];
#pragma unroll
            for (int t = 0; t < 8; ++t) {       // 8B-aligned b64 reads
                const h2x2 qa = *(const h2x2*)(r01 + 2 * t);
                w01[2*t] = qa.a; w01[2*t+1] = qa.b;
                const h2x2 qb = *(const h2x2*)(r23 + 2 * t);
                w23[2*t] = qb.a; w23[2*t+1] = qb.b;
                const __half2 qc = *(const __half2*)(r4 + 2 * t); // b32
                w4[2*t] = __low2half(qc); w4[2*t+1] = __high2half(qc);
            }
        }
#pragma unroll
        for (int k = 0; k < 6; ++k) {
            __half2 s01 = __half2half2(__float2half_rn(0.0f));
            __half2 s23 = s01;
            __half  s4  = __float2half_rn(0.0f);
#pragma unroll
            for (int j = 0; j < 11; ++j) {
                s01 = __hfma2(WH2[j], w01[k + j], s01);
                s23 = __hfma2(WH2[j], w23[k + j], s23);
                s4  = __hfma(WH[j], w4[k + j], s4);
            }
            const float mu1 = __low2float(s01);
            const float mu2 = __high2float(s01);
            const float sxx = __low2float(s23);
            const float syy = __high2float(s23);
            const float sxy = __half2float(s4);
            const float mu1sq = mu1 * mu1;
            const float mu2sq = mu2 * mu2;
            const float mu12  = mu1 * mu2;
            const float num = (2.0f * mu12 + C1c) * (2.0f * (sxy - mu12) + C2c);
            const float den = (mu1sq + mu2sq + C1c) *
                              ((sxx - mu1sq) + (syy - mu2sq) + C2c);
            ssim_acc = fmaf(num, __builtin_amdgcn_rcpf(den), ssim_acc);
        }
    }

    // ---------------- Reduction -> slotted atomics ------------------------
    float v0 = mae_num, v1 = mae_den, v2 = ssim_acc;
#pragma unroll
    for (int off = 32; off >= 1; off >>= 1) {
        v0 += __shfl_down(v0, off);
        v1 += __shfl_down(v1, off);
        v2 += __shfl_down(v2, off);
    }
    if (lane == 0) { red[g][0] = v0; red[g][1] = v1; red[g][2] = v2; }
    __syncthreads();
    if (tid == 0) {
        float r0s = 0.f, r1s = 0.f, r2s = 0.f;
#pragma unroll
        for (int w = 0; w < 4; ++w) {
            r0s += red[w][0]; r1s += red[w][1]; r2s += red[w][2];
        }
        const int slot = logical & (NSLOT - 1);
        atomicAdd(&ws[slot * 3 + 0], r0s);
        atomicAdd(&ws[slot * 3 + 1], r1s);
        atomicAdd(&ws[slot * 3 + 2], r2s);
    }
}

__global__ void finalize_kernel(const float* __restrict__ ws, float* __restrict__ out) {
    if (threadIdx.x == 0 && blockIdx.x == 0) {
        float r0 = 0.f, r1 = 0.f, r2 = 0.f;
        for (int i = 0; i < NSLOT; ++i) {
            r0 += ws[i * 3 + 0];
            r1 += ws[i * 3 + 1];
            r2 += ws[i * 3 + 2];
        }
        const float mae = r0 / (r1 + 1e-8f);
        const float ssim_mean = r2 * (1.0f / 11943936.0f);  // 4096 * 54 * 54
        out[0] = 0.5f * mae + 0.5f * (1.0f - ssim_mean);
    }
}

extern "C" void kernel_launch(void* const* d_in, const int* in_sizes, int n_in,
                              void* d_out, int out_size, void* d_ws, size_t ws_size,
                              hipStream_t stream) {
    const float* in   = (const float*)d_in[0];
    const float* outp = (const float*)d_in[1];
    const float* tgt  = (const float*)d_in[2];
    float* ws = (float*)d_ws;

    hipMemsetAsync(d_ws, 0, NSLOT * 3 * sizeof(float), stream);
    fused_loss_kernel<<<8192, 256, 0, stream>>>(in, outp, tgt, ws);
    finalize_kernel<<<1, 64, 0, stream>>>(ws, (float*)d_out);
}

// Round 17
// 72.293 us; speedup vs baseline: 1.5427x; 1.0410x over previous
//
#include <hip/hip_runtime.h>
#include <hip/hip_fp16.h>

// Fused WeightedMAE + Patch-SSIM loss for (8,8,512,512) fp32 inputs.
// R17 = R14 (best, 75us) with ADDRESS-STREAMING block order.
// Diagnosis: dur ~= FETCH/1.3 TB/s invariant across R10-R16 while VALU
// busy-time varied -> fetch path is co-limiting. Old swizzle stepped ch
// (256 KB jumps) between consecutive blocks on an XCD. New order: XCD k
// owns batch image b=k; within XCD, pw varies fastest, then half, ph, ch
// -> 8 consecutive blocks read the SAME 37 rows across adjacent 256B
// windows = contiguous 2KB spans; halves' 10-row overlap stays L2-hot.
// Kernel body identical to R14: single barrier, wave-local V->H.
// 8192 blocks x 256 threads; LDS 26.8 KB (5 blocks/CU by LDS).

#define C1c 1.0e-4f
#define C2c 9.0e-4f
#define NSLOT 64

struct alignas(16) xy4  { __half2 v[4]; };
struct alignas(8)  h2x2 { __half2 a, b; };

__global__ __launch_bounds__(256)
void fused_loss_kernel(const float* __restrict__ in,
                       const float* __restrict__ outp,
                       const float* __restrict__ tgt,
                       float* __restrict__ ws) {
    __shared__ alignas(16) __half2 xyt[37][64];   // (x,y) per pixel
    __shared__ alignas(16) __half2 V01[27][66];   // (Gv*x, Gv*y), padded
    __shared__ alignas(16) __half2 V23[27][66];   // (Gv*xx, Gv*yy), padded
    __shared__ alignas(16) __half  V4 [27][68];   // Gv*xy
    __shared__ float red[4][3];

    // exp(-(j-5)^2/4.5)/sum, float32 pipeline (HW-validated)
    const float WGT[11] = {0.00102838f, 0.00759874f, 0.03600076f, 0.10936068f,
                           0.21300564f, 0.26601172f, 0.21300564f, 0.10936068f,
                           0.03600076f, 0.00759874f, 0.00102838f};
    __half  WH[11];
    __half2 WH2[11];
#pragma unroll
    for (int j = 0; j < 11; ++j) {       // constant-folded
        WH[j]  = __float2half_rn(WGT[j]);
        WH2[j] = __half2half2(WH[j]);
    }

    const int tid = threadIdx.x;

    // Address-streaming decomposition: XCD k (= orig%8) gets image b=k;
    // within XCD, i sweeps (ch, ph, half, pw) with pw fastest.
    const int orig = blockIdx.x;                 // 0..8191
    const int b    = orig & 7;                   // XCD-aligned batch image
    const int i    = orig >> 3;                  // 0..1023
    const int ch   = i >> 7;                     // 0..7
    const int ph   = (i >> 4) & 7;               // 0..7
    const int half = (i >> 3) & 1;               // 0..1
    const int pw   = i & 7;                      // 0..7  (fastest)
    const int r0   = half ? 27 : 0;

    // ---------------- Phase A: float4 load 37 rows, stage, fused MAE ------
    float mae_num = 0.0f, mae_den = 0.0f;
    const size_t img_base =
        ((size_t)(b * 8 + ch) * 512 + (size_t)(ph * 64 + r0)) * 512 +
        (size_t)(pw * 64);

#pragma unroll
    for (int it = 0; it < 3; ++it) {
        const int slot = tid + it * 256;        // 0..591
        if (slot < 592) {
            const int r  = slot >> 4;           // 0..36
            const int c4 = (slot & 15) << 2;    // 0..60
            const size_t off = img_base + (size_t)r * 512 + (size_t)c4;
            const float4 iv = *(const float4*)(in   + off);
            const float4 ov = *(const float4*)(outp + off);
            const float4 tv = *(const float4*)(tgt  + off);
            xy4 q;
            q.v[0] = __floats2half2_rn(iv.x + ov.x, tv.x);
            q.v[1] = __floats2half2_rn(iv.y + ov.y, tv.y);
            q.v[2] = __floats2half2_rn(iv.z + ov.z, tv.z);
            q.v[3] = __floats2half2_rn(iv.w + ov.w, tv.w);
            *(xy4*)&xyt[r][c4] = q;
            const bool own = half ? (r >= 5) : (r < 32);
            if (own) {
                float hp, w;
                hp = tv.x - iv.x; w = (fabsf(hp) > 0.0f) ? 1.0f : 0.0f;
                mae_den += w; mae_num = fmaf(w, fabsf(ov.x - hp), mae_num);
                hp = tv.y - iv.y; w = (fabsf(hp) > 0.0f) ? 1.0f : 0.0f;
                mae_den += w; mae_num = fmaf(w, fabsf(ov.y - hp), mae_num);
                hp = tv.z - iv.z; w = (fabsf(hp) > 0.0f) ? 1.0f : 0.0f;
                mae_den += w; mae_num = fmaf(w, fabsf(ov.z - hp), mae_num);
                hp = tv.w - iv.w; w = (fabsf(hp) > 0.0f) ? 1.0f : 0.0f;
                mae_den += w; mae_num = fmaf(w, fabsf(ov.w - hp), mae_num);
            }
        }
    }
    __syncthreads();                            // the ONLY barrier

    const int lane = tid & 63;
    const int g    = tid >> 6;                  // wave index, uniform
    const int rb   = g * 7;                     // first owned out row
    const int nrows = (g == 3) ? 6 : 7;

    // ---------------- Phase V: vertical conv, wave-local rows -------------
    {
        const int c     = lane;
        const int nread = (g == 3) ? 16 : 17;

        __half2 a01[7], a23[7];
        __half  a4[7];
#pragma unroll
        for (int i2 = 0; i2 < 7; ++i2) {
            a01[i2] = __half2half2(__float2half_rn(0.0f));
            a23[i2] = a01[i2];
            a4[i2]  = __float2half_rn(0.0f);
        }
#pragma unroll
        for (int ir = 0; ir < 17; ++ir) {
            if (ir < nread) {                   // wave-uniform
                const __half2 q  = xyt[rb + ir][c];
                const __half2 qq = __hmul2(q, q);
                const __half  xyh = __hmul(__low2half(q), __high2half(q));
#pragma unroll
                for (int i2 = 0; i2 < 7; ++i2) {
                    const int j = ir - i2;
                    if (j >= 0 && j <= 10) {    // folds at compile time
                        if (i2 < 6 || g < 3) {  // wave-uniform (i2==6 only)
                            a01[i2] = __hfma2(WH2[j], q,  a01[i2]);
                            a23[i2] = __hfma2(WH2[j], qq, a23[i2]);
                            a4[i2]  = __hfma(WH[j], xyh, a4[i2]);
                        }
                    }
                }
            }
        }
#pragma unroll
        for (int i2 = 0; i2 < 7; ++i2) {
            if (i2 < 6 || g < 3) {
                V01[rb + i2][c] = a01[i2];
                V23[rb + i2][c] = a23[i2];
                V4 [rb + i2][c] = a4[i2];
            }
        }
    }
    // NO BARRIER: wave g reads back only rows rb..rb+nrows-1, which this
    // same wave wrote; LDS ops are in-order within a wave (lgkmcnt).

    // ---------------- Phase H: wave-local horizontal conv + SSIM ----------
    // nrows x 9 groups (6 out cols) = 63 (54) units on 64 lanes.
    float ssim_acc = 0.0f;
    if (lane < nrows * 9) {
        const int row_l = lane / 9;
        const int grp   = lane - row_l * 9;
        const int row   = rb + row_l;
        const int c0    = grp * 6;              // 0,6,..,48

        __half2 w01[16], w23[16];
        __half  w4[16];
        {
            const __half2* r01 = &V01[row][c0];
            const __half2* r23 = &V23[row][c0];
            const __half*  r4  = &V4 [row][c0];
#pragma unroll
            for (int t = 0; t < 8; ++t) {       // 8B-aligned b64 reads
                const h2x2 qa = *(const h2x2*)(r01 + 2 * t);
                w01[2*t] = qa.a; w01[2*t+1] = qa.b;
                const h2x2 qb = *(const h2x2*)(r23 + 2 * t);
                w23[2*t] = qb.a; w23[2*t+1] = qb.b;
                const __half2 qc = *(const __half2*)(r4 + 2 * t); // b32
                w4[2*t] = __low2half(qc); w4[2*t+1] = __high2half(qc);
            }
        }
#pragma unroll
        for (int k = 0; k < 6; ++k) {
            __half2 s01 = __half2half2(__float2half_rn(0.0f));
            __half2 s23 = s01;
            __half  s4  = __float2half_rn(0.0f);
#pragma unroll
            for (int j = 0; j < 11; ++j) {
                s01 = __hfma2(WH2[j], w01[k + j], s01);
                s23 = __hfma2(WH2[j], w23[k + j], s23);
                s4  = __hfma(WH[j], w4[k + j], s4);
            }
            const float mu1 = __low2float(s01);
            const float mu2 = __high2float(s01);
            const float sxx = __low2float(s23);
            const float syy = __high2float(s23);
            const float sxy = __half2float(s4);
            const float mu1sq = mu1 * mu1;
            const float mu2sq = mu2 * mu2;
            const float mu12  = mu1 * mu2;
            const float num = (2.0f * mu12 + C1c) * (2.0f * (sxy - mu12) + C2c);
            const float den = (mu1sq + mu2sq + C1c) *
                              ((sxx - mu1sq) + (syy - mu2sq) + C2c);
            ssim_acc = fmaf(num, __builtin_amdgcn_rcpf(den), ssim_acc);
        }
    }

    // ---------------- Reduction -> slotted atomics ------------------------
    float v0 = mae_num, v1 = mae_den, v2 = ssim_acc;
#pragma unroll
    for (int off = 32; off >= 1; off >>= 1) {
        v0 += __shfl_down(v0, off);
        v1 += __shfl_down(v1, off);
        v2 += __shfl_down(v2, off);
    }
    if (lane == 0) { red[g][0] = v0; red[g][1] = v1; red[g][2] = v2; }
    __syncthreads();
    if (tid == 0) {
        float r0s = 0.f, r1s = 0.f, r2s = 0.f;
#pragma unroll
        for (int w = 0; w < 4; ++w) {
            r0s += red[w][0]; r1s += red[w][1]; r2s += red[w][2];
        }
        const int slot = orig & (NSLOT - 1);
        atomicAdd(&ws[slot * 3 + 0], r0s);
        atomicAdd(&ws[slot * 3 + 1], r1s);
        atomicAdd(&ws[slot * 3 + 2], r2s);
    }
}

__global__ void finalize_kernel(const float* __restrict__ ws, float* __restrict__ out) {
    if (threadIdx.x == 0 && blockIdx.x == 0) {
        float r0 = 0.f, r1 = 0.f, r2 = 0.f;
        for (int i = 0; i < NSLOT; ++i) {
            r0 += ws[i * 3 + 0];
            r1 += ws[i * 3 + 1];
            r2 += ws[i * 3 + 2];
        }
        const float mae = r0 / (r1 + 1e-8f);
        const float ssim_mean = r2 * (1.0f / 11943936.0f);  // 4096 * 54 * 54
        out[0] = 0.5f * mae + 0.5f * (1.0f - ssim_mean);
    }
}

extern "C" void kernel_launch(void* const* d_in, const int* in_sizes, int n_in,
                              void* d_out, int out_size, void* d_ws, size_t ws_size,
                              hipStream_t stream) {
    const float* in   = (const float*)d_in[0];
    const float* outp = (const float*)d_in[1];
    const float* tgt  = (const float*)d_in[2];
    float* ws = (float*)d_ws;

    hipMemsetAsync(d_ws, 0, NSLOT * 3 * sizeof(float), stream);
    fused_loss_kernel<<<8192, 256, 0, stream>>>(in, outp, tgt, ws);
    finalize_kernel<<<1, 64, 0, stream>>>(ws, (float*)d_out);
}